// Round 14
// baseline (88.138 us; speedup 1.0000x reference)
//
#include <hip/hip_runtime.h>
#include <hip/hip_bf16.h>

// Problem constants (from reference)
#define B_    8
#define C_    128
#define H_    64
#define W_    64
#define COUT_ 128
#define K2_   9
#define JOFF_ 18            // 2*K*K offset channels
#define HW_   (H_*W_)       // 4096
#define CK_   (C_*K2_)      // 1152

typedef short  short8 __attribute__((ext_vector_type(8)));   // 8 bf16 in 4 VGPR
typedef float  f32x4  __attribute__((ext_vector_type(4)));
typedef float  f32x16 __attribute__((ext_vector_type(16)));

__device__ __forceinline__ ushort f2bf(float f) {
    __hip_bfloat16 h = __float2bfloat16(f);
    return *reinterpret_cast<ushort*>(&h);
}
__device__ __forceinline__ float bf2f(ushort u) {
    return __uint_as_float(((uint)u) << 16);
}

// ---------------------------------------------------------------------------
// Kernel X: x NCHW f32 -> xt NHWC bf16 ([b][hw][c], c fastest).
// ---------------------------------------------------------------------------
__global__ __launch_bounds__(512) void nhwc_kernel(
    const float* __restrict__ x, ushort* __restrict__ xt)
{
    __shared__ float tile[64][65];
    const int blk = blockIdx.x;            // 8 b * 2 ct * 64 ht = 1024
    const int ht = blk & 63;
    const int ct = (blk >> 6) & 1;
    const int b  = blk >> 7;
    const int t  = threadIdx.x;
    const int tx = t & 63, ty = t >> 6;    // ty 0..7

    const float* xs = x + ((size_t)(b * C_ + ct * 64) << 12) + (ht << 6);
#pragma unroll
    for (int i = 0; i < 8; ++i) {
        int c = i * 8 + ty;
        tile[c][tx] = xs[((size_t)c << 12) + tx];
    }
    __syncthreads();

    const int r  = t >> 3;                 // position 0..63
    const int co = (t & 7) * 8;            // channel octet
    short8 pack;
#pragma unroll
    for (int j = 0; j < 8; ++j) pack[j] = (short)f2bf(tile[co + j][r]);
    *reinterpret_cast<short8*>(
        xt + ((((size_t)b << 12) + (ht << 6) + r) << 7) + ct * 64 + co) = pack;
}

// ---------------------------------------------------------------------------
// Kernel T: both weight transposes.
//   wt     [k][o][c]  bf16 (tap-major)             deform GEMM A
//   wt_off [k][j32][c] bf16 (tap-major, rows 18..31 zero)  offset GEMM A
// ---------------------------------------------------------------------------
__global__ __launch_bounds__(256) void transpose_w_kernel(
    const float* __restrict__ w_def, const float* __restrict__ w_off,
    ushort* __restrict__ wt, ushort* __restrict__ wt_off)
{
    int t = blockIdx.x * 256 + threadIdx.x;
    if (t < K2_ * COUT_ * C_) {
        int c = t & 127;
        int o = (t >> 7) & 127;
        int k = t >> 14;
        float v = w_def[((size_t)o * C_ + c) * K2_ + k];
        wt[((size_t)k * COUT_ + o) * C_ + c] = f2bf(v);
    } else {
        int i = t - K2_ * COUT_ * C_;
        if (i < K2_ * 32 * C_) {
            int c = i & 127;
            int j = (i >> 7) & 31;
            int k = i >> 12;
            float v = (j < JOFF_) ? w_off[((size_t)j * C_ + c) * K2_ + k] : 0.f;
            wt_off[(((size_t)k * 32) + j) * C_ + c] = f2bf(v);
        }
    }
}

// ---------------------------------------------------------------------------
// Kernel B: offset conv (MFMA prologue) + fused gather + MFMA GEMM.
// r13 skeleton (tile 128x64, 512 blocks, 8 waves, TA-coalesced gather),
// but einsum MFMA switched 16x16x32 -> 32x32x16: 2x FLOP per LDS byte.
// Wave = one 32x32 tile: rows miW*32 (miW=wid>>1), cols niW*32 (niW=wid&1).
// Per wave per tap: 8 kc-steps x [1 ds_read_b128 B + 1 MFMA].
// Block LDS/tap: reads 64KB (was 128KB) + writes 16KB.
// A single-buffered: aC[8] reloaded for k+1 AFTER MFMA(k) (sched_barrier).
// ---------------------------------------------------------------------------
__global__ __launch_bounds__(512, 4) void deform_mfma_kernel(
    const ushort* __restrict__ xt, const ushort* __restrict__ wt,
    const ushort* __restrict__ wt_off, const float* __restrict__ b_off,
    float* __restrict__ out)
{
    __shared__ ushort sB[2][64][C_];         // 32 KB, XOR-swizzled
    __shared__ float  s_off[JOFF_][64];      // 4.6 KB offsets for this row

    const int bid  = blockIdx.x;             // 512 blocks
    const int nbid = ((bid & 7) << 6) + (bid >> 3);   // XCD chunk: 1 image/XCD
    const int s0   = nbid << 6;
    const int b    = s0 >> 12;
    const int hw0  = s0 & (HW_ - 1);
    const int ho   = hw0 >> 6;

    const int t    = threadIdx.x;
    const int wid  = t >> 6, lane = t & 63;
    const int arow = lane & 15;              // prologue (16x16) lane coords
    const int akk  = (lane >> 4) << 3;
    const int gp   = t >> 3;                 // gather position 0..63
    const int gq   = t & 7;                  // gather chunk (8 ch) 0..7
    const int swzp = (gp & 15) << 3;
    const ushort* xtb = xt + ((size_t)b << 19);   // b * 4096 * 128

    // ================= offset-conv MFMA prologue (16x16, unchanged) ==========
    {
        const int wmO = wid >> 2, wnO = wid & 3;  // M=32 (2x16), N=64 (4x16)
        f32x4 o0 = {}, o1 = {};
        const int sxb = wnO * 16 + arow - 1;      // image col for kx=0
#pragma unroll
        for (int k = 0; k < K2_; ++k) {
            const int ky = k / 3, kx = k % 3;
            const int yr = ho - 1 + ky;
            const int sx = sxb + kx;
            const bool inb = (yr >= 0) && (yr < H_) && (sx >= 0) && (sx < W_);
            const ushort* bp = xtb + (((size_t)((yr << 6) + sx)) << 7) + akk;
            const ushort* ap = wt_off + (((size_t)(k * 32 + wmO * 16 + arow)) << 7) + akk;
#pragma unroll
            for (int kc = 0; kc < 4; ++kc) {
                short8 bO = {};
                if (inb) bO = *reinterpret_cast<const short8*>(bp + kc * 32);
                short8 aO = *reinterpret_cast<const short8*>(ap + kc * 32);
                if (kc < 2) o0 = __builtin_amdgcn_mfma_f32_16x16x32_bf16(aO, bO, o0, 0, 0, 0);
                else        o1 = __builtin_amdgcn_mfma_f32_16x16x32_bf16(aO, bO, o1, 0, 0, 0);
            }
        }
        const int sO = wnO * 16 + arow;
#pragma unroll
        for (int r4 = 0; r4 < 4; ++r4) {
            int j = wmO * 16 + ((lane >> 4) << 2) + r4;
            if (j < JOFF_) s_off[j][sO] = o0[r4] + o1[r4] + b_off[j];
        }
    }
    __syncthreads();

    // ================= fused gather + MFMA main loop (32x32x16) ==============
    const int miW  = wid >> 1;               // 0..3: out-ch tile (32 rows)
    const int niW  = wid & 1;                // 0..1: position tile (32 cols)
    const int ar32 = lane & 31;              // A/B row-col within 32-tile
    const int ak16 = (lane >> 5) << 3;       // k-offset 0 or 8 within K=16

    f32x16 acc = {};
    short8 aC[8];
    short8 g[4][2];                          // [corner 00,01,10,11][chunk j]
    float  ca00, ca01, ca10, ca11;

    auto load_a = [&](int k) {
        const ushort* wk = wt + (size_t)k * (COUT_ * C_)
                         + (miW * 32 + ar32) * C_ + ak16;
#pragma unroll
        for (int kc = 0; kc < 8; ++kc)
            aC[kc] = *reinterpret_cast<const short8*>(wk + kc * 16);
    };

    // issue 8 lane-adjacent 16B corner loads (16 ch: chunks gq, gq+8)
    auto gather_load = [&](int k) {
        float dy = s_off[2*k    ][gp];
        float dx = s_off[2*k + 1][gp];
        float py = (float)(ho - 1 + k/3) + dy;
        float px = (float)(gp - 1 + k%3) + dx;
        float y0f = floorf(py), x0f = floorf(px);
        float wy = py - y0f,    wx = px - x0f;
        int y0 = (int)y0f, x0 = (int)x0f;
        int y1 = y0 + 1,   x1 = x0 + 1;
        float vy0 = (y0 >= 0 && y0 < H_) ? 1.f : 0.f;
        float vy1 = (y1 >= 0 && y1 < H_) ? 1.f : 0.f;
        float vx0 = (x0 >= 0 && x0 < W_) ? 1.f : 0.f;
        float vx1 = (x1 >= 0 && x1 < W_) ? 1.f : 0.f;
        int y0c = min(max(y0, 0), H_-1), y1c = min(max(y1, 0), H_-1);
        int x0c = min(max(x0, 0), W_-1), x1c = min(max(x1, 0), W_-1);
        int bx  = min(max(x0, 0), W_-2);     // column pair [bx, bx+1]
        float wx0 = (1.f - wx) * vx0, wx1 = wx * vx1;
        float ex0 = (x0c == bx ? wx0 : 0.f) + (x1c == bx ? wx1 : 0.f);
        float ex1 = (x0c == bx ? 0.f : wx0) + (x1c == bx ? 0.f : wx1);
        float r0 = (1.f - wy) * vy0, r1 = wy * vy1;
        ca00 = r0*ex0; ca01 = r0*ex1; ca10 = r1*ex0; ca11 = r1*ex1;
        const ushort* r00 = xtb + (((y0c << 6) + bx) << 7) + gq * 8;
        const ushort* r10 = xtb + (((y1c << 6) + bx) << 7) + gq * 8;
        g[0][0] = *reinterpret_cast<const short8*>(r00);        // (y0,bx)  lo
        g[0][1] = *reinterpret_cast<const short8*>(r00 + 64);   // (y0,bx)  hi
        g[1][0] = *reinterpret_cast<const short8*>(r00 + 128);  // (y0,bx+1)lo
        g[1][1] = *reinterpret_cast<const short8*>(r00 + 192);  // (y0,bx+1)hi
        g[2][0] = *reinterpret_cast<const short8*>(r10);        // (y1,bx)  lo
        g[2][1] = *reinterpret_cast<const short8*>(r10 + 64);   // (y1,bx)  hi
        g[3][0] = *reinterpret_cast<const short8*>(r10 + 128);  // (y1,bx+1)lo
        g[3][1] = *reinterpret_cast<const short8*>(r10 + 192);  // (y1,bx+1)hi
    };

    // combine corners, pack, two b128 stores (chunks gq, gq+8)
    auto gather_math_store = [&](int buf) {
#pragma unroll
        for (int j = 0; j < 2; ++j) {
            float v[8];
#pragma unroll
            for (int q = 0; q < 8; ++q) {
                float vv = ca00 * bf2f((ushort)g[0][j][q]);
                vv = fmaf(ca01, bf2f((ushort)g[1][j][q]), vv);
                vv = fmaf(ca10, bf2f((ushort)g[2][j][q]), vv);
                vv = fmaf(ca11, bf2f((ushort)g[3][j][q]), vv);
                v[q] = vv;
            }
            uint4 pk;
            pk.x = (uint)f2bf(v[0]) | ((uint)f2bf(v[1]) << 16);
            pk.y = (uint)f2bf(v[2]) | ((uint)f2bf(v[3]) << 16);
            pk.z = (uint)f2bf(v[4]) | ((uint)f2bf(v[5]) << 16);
            pk.w = (uint)f2bf(v[6]) | ((uint)f2bf(v[7]) << 16);
            *reinterpret_cast<uint4*>(
                &sB[buf][gp][(gq * 8 + j * 64) ^ swzp]) = pk;
        }
    };

    // ---- prologue
    load_a(0);
    gather_load(0);
    gather_math_store(0);
    asm volatile("s_waitcnt lgkmcnt(0)" ::: "memory");
    __builtin_amdgcn_s_barrier();

    for (int k = 0; k < K2_; ++k) {
        if (k < K2_ - 1) gather_load(k + 1);     // oldest VMEM this iter

        // ---- MFMA(k): 8 x [ds_read_b128 B + mfma_32x32x16], A in aC regs
        const int buf = k & 1;
        const int brow = niW * 32 + ar32;
        const int bkey = (brow & 15) << 3;
#pragma unroll
        for (int kc = 0; kc < 8; ++kc) {
            short8 bF = *reinterpret_cast<const short8*>(
                &sB[buf][brow][(kc * 16 + ak16) ^ bkey]);
            acc = __builtin_amdgcn_mfma_f32_32x32x16_bf16(aC[kc], bF, acc, 0, 0, 0);
        }

        // keep the aC reload BELOW MFMA(k) so one buffer suffices
        __builtin_amdgcn_sched_barrier(0);

        if (k < K2_ - 1) {
            load_a(k + 1);                       // overwrites aC (now dead)
            gather_math_store((k + 1) & 1);      // waits g only (A newer)
        }

        // RAW barrier: drain LDS ops only; VMEM prefetches stay in flight
        asm volatile("s_waitcnt lgkmcnt(0)" ::: "memory");
        __builtin_amdgcn_s_barrier();
    }

    // ---- epilogue: 32x32 C/D layout col=lane&31, row=(reg&3)+8*(reg>>2)+4*(lane>>5)
    const int sC = niW * 32 + ar32;
#pragma unroll
    for (int q = 0; q < 4; ++q) {
#pragma unroll
        for (int j = 0; j < 4; ++j) {
            int o = miW * 32 + j + q * 8 + ((lane >> 5) << 2);
            __builtin_nontemporal_store(acc[q * 4 + j],
                &out[(((size_t)(b * COUT_ + o)) << 12) + hw0 + sC]);
        }
    }
}

// ---------------------------------------------------------------------------
extern "C" void kernel_launch(void* const* d_in, const int* in_sizes, int n_in,
                              void* d_out, int out_size, void* d_ws, size_t ws_size,
                              hipStream_t stream) {
    const float* x     = (const float*)d_in[0];
    const float* w_off = (const float*)d_in[1];
    const float* b_off = (const float*)d_in[2];
    const float* w_def = (const float*)d_in[3];
    float* out  = (float*)d_out;

    char* ws = (char*)d_ws;
    ushort* xtp    = (ushort*)ws;                         // 8,388,608 B
    ushort* wt     = (ushort*)(ws + 8388608);             //   294,912 B
    ushort* wt_off = (ushort*)(ws + 8388608 + 294912);    //    73,728 B

    // Kernel X: x -> NHWC bf16
    nhwc_kernel<<<1024, 512, 0, stream>>>(x, xtp);
    // Kernel T: both weight transposes
    {
        int total  = K2_ * COUT_ * C_ + K2_ * 32 * C_;    // 184,320
        transpose_w_kernel<<<(total + 255) / 256, 256, 0, stream>>>(
            w_def, w_off, wt, wt_off);
    }
    // Kernel B: fused offsets + gather + MFMA GEMM (512 blocks, 64 pos each)
    deform_mfma_kernel<<<(B_ * HW_) / 64, 512, 0, stream>>>(
        xtp, wt, wt_off, b_off, out);
}

// Round 15
// 64.140 us; speedup vs baseline: 1.3742x; 1.3742x over previous
//
#include <hip/hip_runtime.h>
#include <hip/hip_bf16.h>

// Problem constants (from reference)
#define B_    8
#define C_    128
#define H_    64
#define W_    64
#define COUT_ 128
#define K2_   9
#define JOFF_ 18            // 2*K*K offset channels
#define HW_   (H_*W_)       // 4096
#define CK_   (C_*K2_)      // 1152

typedef short  short8 __attribute__((ext_vector_type(8)));   // 8 bf16 in 4 VGPR
typedef float  f32x4  __attribute__((ext_vector_type(4)));

__device__ __forceinline__ ushort f2bf(float f) {
    __hip_bfloat16 h = __float2bfloat16(f);
    return *reinterpret_cast<ushort*>(&h);
}
__device__ __forceinline__ float bf2f(ushort u) {
    return __uint_as_float(((uint)u) << 16);
}

// ---------------------------------------------------------------------------
// Kernel X: x NCHW f32 -> xt NHWC bf16 ([b][hw][c], c fastest).
// ---------------------------------------------------------------------------
__global__ __launch_bounds__(512) void nhwc_kernel(
    const float* __restrict__ x, ushort* __restrict__ xt)
{
    __shared__ float tile[64][65];
    const int blk = blockIdx.x;            // 8 b * 2 ct * 64 ht = 1024
    const int ht = blk & 63;
    const int ct = (blk >> 6) & 1;
    const int b  = blk >> 7;
    const int t  = threadIdx.x;
    const int tx = t & 63, ty = t >> 6;    // ty 0..7

    const float* xs = x + ((size_t)(b * C_ + ct * 64) << 12) + (ht << 6);
#pragma unroll
    for (int i = 0; i < 8; ++i) {
        int c = i * 8 + ty;
        tile[c][tx] = xs[((size_t)c << 12) + tx];
    }
    __syncthreads();

    const int r  = t >> 3;                 // position 0..63
    const int co = (t & 7) * 8;            // channel octet
    short8 pack;
#pragma unroll
    for (int j = 0; j < 8; ++j) pack[j] = (short)f2bf(tile[co + j][r]);
    *reinterpret_cast<short8*>(
        xt + ((((size_t)b << 12) + (ht << 6) + r) << 7) + ct * 64 + co) = pack;
}

// ---------------------------------------------------------------------------
// Kernel T: both weight transposes.
//   wt     [k][o][c]  bf16 (tap-major)             deform GEMM A
//   wt_off [k][j32][c] bf16 (tap-major, rows 18..31 zero)  offset GEMM A
// ---------------------------------------------------------------------------
__global__ __launch_bounds__(256) void transpose_w_kernel(
    const float* __restrict__ w_def, const float* __restrict__ w_off,
    ushort* __restrict__ wt, ushort* __restrict__ wt_off)
{
    int t = blockIdx.x * 256 + threadIdx.x;
    if (t < K2_ * COUT_ * C_) {
        int c = t & 127;
        int o = (t >> 7) & 127;
        int k = t >> 14;
        float v = w_def[((size_t)o * C_ + c) * K2_ + k];
        wt[((size_t)k * COUT_ + o) * C_ + c] = f2bf(v);
    } else {
        int i = t - K2_ * COUT_ * C_;
        if (i < K2_ * 32 * C_) {
            int c = i & 127;
            int j = (i >> 7) & 31;
            int k = i >> 12;
            float v = (j < JOFF_) ? w_off[((size_t)j * C_ + c) * K2_ + k] : 0.f;
            wt_off[(((size_t)k * 32) + j) * C_ + c] = f2bf(v);
        }
    }
}

// ---------------------------------------------------------------------------
// Kernel B: offset conv (LDS-staged MFMA prologue) + fused deformable
// gather + MFMA GEMM. r13 main loop byte-identical (16x16x32, aC/aN dbuf,
// TA-coalesced gather, single RAW barrier/tap).
// NEW prologue: stage the 3 source rows (48KB, zero-guarded cols -1/64,
// XOR-swizzled (row&7)<<3) into LDS once, TA-coalesced; then 36 MFMAs read
// B via conflict-free ds_read_b128 — replaces 288KB/block of 16-line
// scattered VMEM B loads (r13 prologue was ~17us of the 68us kernel).
// pro[3][66][128] (50.7KB) overlays sB (union): sB first written only
// after the prologue's closing barrier.
// ---------------------------------------------------------------------------
__global__ __launch_bounds__(512, 4) void deform_mfma_kernel(
    const ushort* __restrict__ xt, const ushort* __restrict__ wt,
    const ushort* __restrict__ wt_off, const float* __restrict__ b_off,
    float* __restrict__ out)
{
    __shared__ __align__(16) ushort smem[3 * 66 * C_];   // 50688 B union
    __shared__ float s_off[JOFF_][64];                   // 4.6 KB

    typedef ushort sB_t[2][64][C_];                      // 32768 B view
    typedef ushort pro_t[3][66][C_];                     // 50688 B view
    sB_t&  sB  = *reinterpret_cast<sB_t*>(smem);
    pro_t& pro = *reinterpret_cast<pro_t*>(smem);

    const int bid  = blockIdx.x;             // 512 blocks
    const int nbid = ((bid & 7) << 6) + (bid >> 3);   // XCD chunk: 1 image/XCD
    const int s0   = nbid << 6;
    const int b    = s0 >> 12;
    const int hw0  = s0 & (HW_ - 1);
    const int ho   = hw0 >> 6;

    const int t    = threadIdx.x;
    const int wid  = t >> 6, lane = t & 63;
    const int arow = lane & 15;
    const int akk  = (lane >> 4) << 3;
    const int gp   = t >> 3;                 // gather position 0..63
    const int gq   = t & 7;                  // gather chunk (8 ch) 0..7
    const int swzp = (gp & 15) << 3;
    const ushort* xtb = xt + ((size_t)b << 19);   // b * 4096 * 128

    // ================= offset-conv prologue: stage 3 rows =================
    // guard rows q=0 (image col -1) and q=65 (image col 64): zeros
    if (t < 384) {
        int rr  = t >> 7, sub = t & 127;
        int q   = (sub & 64) ? 65 : 0;
        reinterpret_cast<uint*>(&pro[rr][q][0])[sub & 63] = 0u;
    }
    // 3 x 64 x 16 chunk-slots of 16B, TA-coalesced; zero if source row OOB
#pragma unroll
    for (int it = 0; it < 6; ++it) {
        int i   = t + it * 512;
        int rr  = i >> 10;
        int rem = i & 1023;
        int pos = rem >> 4;
        int ch  = rem & 15;
        int yr  = ho - 1 + rr;
        short8 val = {};
        if (yr >= 0 && yr < H_)
            val = *reinterpret_cast<const short8*>(
                xtb + (((size_t)((yr << 6) + pos)) << 7) + ch * 8);
        int q = pos + 1;
        *reinterpret_cast<short8*>(
            &pro[rr][q][(ch * 8) ^ ((q & 7) << 3)]) = val;
    }
    __syncthreads();

    // ================= offset-conv MFMA (B from LDS, no masking) ===========
    {
        const int wmO = wid >> 2, wnO = wid & 3;  // M=32 (2x16), N=64 (4x16)
        const int colq = wnO * 16 + arow;         // output position s
        f32x4 o0 = {}, o1 = {};
#pragma unroll
        for (int k = 0; k < K2_; ++k) {
            const int ky = k / 3, kx = k % 3;
            const int qr  = colq + kx;            // LDS row = s + kx (0..65)
            const int key = (qr & 7) << 3;
            const ushort* ap = wt_off
                + (((size_t)(k * 32 + wmO * 16 + arow)) << 7) + akk;
#pragma unroll
            for (int kc = 0; kc < 4; ++kc) {
                short8 aO = *reinterpret_cast<const short8*>(ap + kc * 32);
                short8 bO = *reinterpret_cast<const short8*>(
                    &pro[ky][qr][(kc * 32 + akk) ^ key]);
                if (kc < 2) o0 = __builtin_amdgcn_mfma_f32_16x16x32_bf16(aO, bO, o0, 0, 0, 0);
                else        o1 = __builtin_amdgcn_mfma_f32_16x16x32_bf16(aO, bO, o1, 0, 0, 0);
            }
        }
        const int sO = wnO * 16 + arow;
#pragma unroll
        for (int r4 = 0; r4 < 4; ++r4) {
            int j = wmO * 16 + ((lane >> 4) << 2) + r4;
            if (j < JOFF_) s_off[j][sO] = o0[r4] + o1[r4] + b_off[j];
        }
    }
    __syncthreads();   // publishes s_off; retires pro (sB may now be written)

    // ================= fused gather + MFMA main loop (r13) =================
    f32x4  acc[4] = {};
    short8 aC[4], aN[4];
    short8 g[4][2];                          // [corner 00,01,10,11][chunk j]
    float  ca00, ca01, ca10, ca11;

    auto load_a = [&](int k, short8* dst) {
        const ushort* wk = wt + (size_t)k * (COUT_ * C_)
                         + (wid * 16 + arow) * C_ + akk;
#pragma unroll
        for (int kc = 0; kc < 4; ++kc)
            dst[kc] = *reinterpret_cast<const short8*>(wk + kc * 32);
    };

    // issue 8 lane-adjacent 16B corner loads (16 ch: chunks gq, gq+8)
    auto gather_load = [&](int k) {
        float dy = s_off[2*k    ][gp];
        float dx = s_off[2*k + 1][gp];
        float py = (float)(ho - 1 + k/3) + dy;
        float px = (float)(gp - 1 + k%3) + dx;
        float y0f = floorf(py), x0f = floorf(px);
        float wy = py - y0f,    wx = px - x0f;
        int y0 = (int)y0f, x0 = (int)x0f;
        int y1 = y0 + 1,   x1 = x0 + 1;
        float vy0 = (y0 >= 0 && y0 < H_) ? 1.f : 0.f;
        float vy1 = (y1 >= 0 && y1 < H_) ? 1.f : 0.f;
        float vx0 = (x0 >= 0 && x0 < W_) ? 1.f : 0.f;
        float vx1 = (x1 >= 0 && x1 < W_) ? 1.f : 0.f;
        int y0c = min(max(y0, 0), H_-1), y1c = min(max(y1, 0), H_-1);
        int x0c = min(max(x0, 0), W_-1), x1c = min(max(x1, 0), W_-1);
        int bx  = min(max(x0, 0), W_-2);     // column pair [bx, bx+1]
        float wx0 = (1.f - wx) * vx0, wx1 = wx * vx1;
        float ex0 = (x0c == bx ? wx0 : 0.f) + (x1c == bx ? wx1 : 0.f);
        float ex1 = (x0c == bx ? 0.f : wx0) + (x1c == bx ? 0.f : wx1);
        float r0 = (1.f - wy) * vy0, r1 = wy * vy1;
        ca00 = r0*ex0; ca01 = r0*ex1; ca10 = r1*ex0; ca11 = r1*ex1;
        const ushort* r00 = xtb + (((y0c << 6) + bx) << 7) + gq * 8;
        const ushort* r10 = xtb + (((y1c << 6) + bx) << 7) + gq * 8;
        g[0][0] = *reinterpret_cast<const short8*>(r00);        // (y0,bx)  lo
        g[0][1] = *reinterpret_cast<const short8*>(r00 + 64);   // (y0,bx)  hi
        g[1][0] = *reinterpret_cast<const short8*>(r00 + 128);  // (y0,bx+1)lo
        g[1][1] = *reinterpret_cast<const short8*>(r00 + 192);  // (y0,bx+1)hi
        g[2][0] = *reinterpret_cast<const short8*>(r10);        // (y1,bx)  lo
        g[2][1] = *reinterpret_cast<const short8*>(r10 + 64);   // (y1,bx)  hi
        g[3][0] = *reinterpret_cast<const short8*>(r10 + 128);  // (y1,bx+1)lo
        g[3][1] = *reinterpret_cast<const short8*>(r10 + 192);  // (y1,bx+1)hi
    };

    // combine corners, pack, two b128 stores (chunks gq, gq+8)
    auto gather_math_store = [&](int buf) {
#pragma unroll
        for (int j = 0; j < 2; ++j) {
            float v[8];
#pragma unroll
            for (int q = 0; q < 8; ++q) {
                float vv = ca00 * bf2f((ushort)g[0][j][q]);
                vv = fmaf(ca01, bf2f((ushort)g[1][j][q]), vv);
                vv = fmaf(ca10, bf2f((ushort)g[2][j][q]), vv);
                vv = fmaf(ca11, bf2f((ushort)g[3][j][q]), vv);
                v[q] = vv;
            }
            uint4 pk;
            pk.x = (uint)f2bf(v[0]) | ((uint)f2bf(v[1]) << 16);
            pk.y = (uint)f2bf(v[2]) | ((uint)f2bf(v[3]) << 16);
            pk.z = (uint)f2bf(v[4]) | ((uint)f2bf(v[5]) << 16);
            pk.w = (uint)f2bf(v[6]) | ((uint)f2bf(v[7]) << 16);
            *reinterpret_cast<uint4*>(
                &sB[buf][gp][(gq * 8 + j * 64) ^ swzp]) = pk;
        }
    };

    // ---- prologue
    load_a(0, aC);
    gather_load(0);
    gather_math_store(0);
    asm volatile("s_waitcnt lgkmcnt(0)" ::: "memory");
    __builtin_amdgcn_s_barrier();

    for (int k = 0; k < K2_; ++k) {
        if (k < K2_ - 1) { gather_load(k + 1); load_a(k + 1, aN); }

        // ---- MFMA(k): LDS B, register A
        const int buf = k & 1;
#pragma unroll
        for (int kc = 0; kc < 4; ++kc) {
#pragma unroll
            for (int ni = 0; ni < 4; ++ni) {
                int srow = ni*16 + arow;
                short8 bF = *reinterpret_cast<const short8*>(
                    &sB[buf][srow][(kc*32 + akk) ^ ((srow & 15) << 3)]);
                acc[ni] = __builtin_amdgcn_mfma_f32_16x16x32_bf16(
                    aC[kc], bF, acc[ni], 0, 0, 0);
            }
        }

        if (k < K2_ - 1) gather_math_store((k + 1) & 1);

        // RAW barrier: drain LDS ops only; VMEM prefetches stay in flight
        asm volatile("s_waitcnt lgkmcnt(0)" ::: "memory");
        __builtin_amdgcn_s_barrier();

        if (k < K2_ - 1) {
#pragma unroll
            for (int kc = 0; kc < 4; ++kc) aC[kc] = aN[kc];
        }
    }

    // ---- epilogue: C/D layout col=lane&15, row=(lane>>4)*4+reg; nt stores
#pragma unroll
    for (int ni = 0; ni < 4; ++ni) {
#pragma unroll
        for (int r = 0; r < 4; ++r) {
            int o = wid*16 + ((lane >> 4) << 2) + r;
            int s = ni*16 + arow;
            __builtin_nontemporal_store(acc[ni][r],
                &out[(((size_t)(b*COUT_ + o)) << 12) + hw0 + s]);
        }
    }
}

// ---------------------------------------------------------------------------
extern "C" void kernel_launch(void* const* d_in, const int* in_sizes, int n_in,
                              void* d_out, int out_size, void* d_ws, size_t ws_size,
                              hipStream_t stream) {
    const float* x     = (const float*)d_in[0];
    const float* w_off = (const float*)d_in[1];
    const float* b_off = (const float*)d_in[2];
    const float* w_def = (const float*)d_in[3];
    float* out  = (float*)d_out;

    char* ws = (char*)d_ws;
    ushort* xtp    = (ushort*)ws;                         // 8,388,608 B
    ushort* wt     = (ushort*)(ws + 8388608);             //   294,912 B
    ushort* wt_off = (ushort*)(ws + 8388608 + 294912);    //    73,728 B

    // Kernel X: x -> NHWC bf16
    nhwc_kernel<<<1024, 512, 0, stream>>>(x, xtp);
    // Kernel T: both weight transposes
    {
        int total  = K2_ * COUT_ * C_ + K2_ * 32 * C_;    // 184,320
        transpose_w_kernel<<<(total + 255) / 256, 256, 0, stream>>>(
            w_def, w_off, wt, wt_off);
    }
    // Kernel B: fused offsets + gather + MFMA GEMM (512 blocks, 64 pos each)
    deform_mfma_kernel<<<(B_ * HW_) / 64, 512, 0, stream>>>(
        xtp, wt, wt_off, b_off, out);
}

// Round 16
// 58.873 us; speedup vs baseline: 1.4971x; 1.0895x over previous
//
#include <hip/hip_runtime.h>
#include <hip/hip_bf16.h>

// Problem constants (from reference)
#define B_    8
#define C_    128
#define H_    64
#define W_    64
#define COUT_ 128
#define K2_   9
#define JOFF_ 18            // 2*K*K offset channels
#define HW_   (H_*W_)       // 4096
#define CK_   (C_*K2_)      // 1152

typedef short  short8 __attribute__((ext_vector_type(8)));   // 8 bf16 in 4 VGPR
typedef float  f32x4  __attribute__((ext_vector_type(4)));

__device__ __forceinline__ ushort f2bf(float f) {
    __hip_bfloat16 h = __float2bfloat16(f);
    return *reinterpret_cast<ushort*>(&h);
}
__device__ __forceinline__ float bf2f(ushort u) {
    return __uint_as_float(((uint)u) << 16);
}

// ---------------------------------------------------------------------------
// Kernel X: x NCHW f32 -> xt NHWC bf16 ([b][hw][c], c fastest).
// ---------------------------------------------------------------------------
__global__ __launch_bounds__(512) void nhwc_kernel(
    const float* __restrict__ x, ushort* __restrict__ xt)
{
    __shared__ float tile[64][65];
    const int blk = blockIdx.x;            // 8 b * 2 ct * 64 ht = 1024
    const int ht = blk & 63;
    const int ct = (blk >> 6) & 1;
    const int b  = blk >> 7;
    const int t  = threadIdx.x;
    const int tx = t & 63, ty = t >> 6;    // ty 0..7

    const float* xs = x + ((size_t)(b * C_ + ct * 64) << 12) + (ht << 6);
#pragma unroll
    for (int i = 0; i < 8; ++i) {
        int c = i * 8 + ty;
        tile[c][tx] = xs[((size_t)c << 12) + tx];
    }
    __syncthreads();

    const int r  = t >> 3;                 // position 0..63
    const int co = (t & 7) * 8;            // channel octet
    short8 pack;
#pragma unroll
    for (int j = 0; j < 8; ++j) pack[j] = (short)f2bf(tile[co + j][r]);
    *reinterpret_cast<short8*>(
        xt + ((((size_t)b << 12) + (ht << 6) + r) << 7) + ct * 64 + co) = pack;
}

// ---------------------------------------------------------------------------
// Kernel T: both weight transposes.
//   wt     [k][o][c]  bf16 (tap-major)             deform GEMM A
//   wt_off [k][j32][c] bf16 (tap-major, rows 18..31 zero)  offset GEMM A
// ---------------------------------------------------------------------------
__global__ __launch_bounds__(256) void transpose_w_kernel(
    const float* __restrict__ w_def, const float* __restrict__ w_off,
    ushort* __restrict__ wt, ushort* __restrict__ wt_off)
{
    int t = blockIdx.x * 256 + threadIdx.x;
    if (t < K2_ * COUT_ * C_) {
        int c = t & 127;
        int o = (t >> 7) & 127;
        int k = t >> 14;
        float v = w_def[((size_t)o * C_ + c) * K2_ + k];
        wt[((size_t)k * COUT_ + o) * C_ + c] = f2bf(v);
    } else {
        int i = t - K2_ * COUT_ * C_;
        if (i < K2_ * 32 * C_) {
            int c = i & 127;
            int j = (i >> 7) & 31;
            int k = i >> 12;
            float v = (j < JOFF_) ? w_off[((size_t)j * C_ + c) * K2_ + k] : 0.f;
            wt_off[(((size_t)k * 32) + j) * C_ + c] = f2bf(v);
        }
    }
}

// ---------------------------------------------------------------------------
// Kernel B: offset conv (LDS-staged MFMA prologue, r15) + fused deformable
// gather + MFMA GEMM with STATIC DEPTH-2 gather pipeline.
// Tap loop fully unrolled: buffer parity (gA/cA vs gB/cB) is compile-time,
// so both buffer sets live in registers (r10's runtime-parity version went
// to scratch — rule #20). Per-iter issue order (vmcnt FIFO verified):
//   load_a(k+1)->aN ; gather(k+2)->buf[k&1] ; MFMA(k) (aC wait: oldest) ;
//   math+store(k+1) from buf[(k+1)&1] (leaves aN + gather(k+2) in flight) ;
//   lgkmcnt(0); s_barrier ; aC<-aN.
// Gathers get ~2 iterations (~1.5K cyc) of latency cover vs r15's ~300.
// ---------------------------------------------------------------------------
__global__ __launch_bounds__(512, 4) void deform_mfma_kernel(
    const ushort* __restrict__ xt, const ushort* __restrict__ wt,
    const ushort* __restrict__ wt_off, const float* __restrict__ b_off,
    float* __restrict__ out)
{
    __shared__ __align__(16) ushort smem[3 * 66 * C_];   // 50688 B union
    __shared__ float s_off[JOFF_][64];                   // 4.6 KB

    typedef ushort sB_t[2][64][C_];                      // 32768 B view
    typedef ushort pro_t[3][66][C_];                     // 50688 B view
    sB_t&  sB  = *reinterpret_cast<sB_t*>(smem);
    pro_t& pro = *reinterpret_cast<pro_t*>(smem);

    const int bid  = blockIdx.x;             // 512 blocks
    const int nbid = ((bid & 7) << 6) + (bid >> 3);   // XCD chunk: 1 image/XCD
    const int s0   = nbid << 6;
    const int b    = s0 >> 12;
    const int hw0  = s0 & (HW_ - 1);
    const int ho   = hw0 >> 6;

    const int t    = threadIdx.x;
    const int wid  = t >> 6, lane = t & 63;
    const int arow = lane & 15;
    const int akk  = (lane >> 4) << 3;
    const int gp   = t >> 3;                 // gather position 0..63
    const int gq   = t & 7;                  // gather chunk (8 ch) 0..7
    const int swzp = (gp & 15) << 3;
    const ushort* xtb = xt + ((size_t)b << 19);   // b * 4096 * 128

    // ================= offset-conv prologue: stage 3 rows =================
    if (t < 384) {
        int rr  = t >> 7, sub = t & 127;
        int q   = (sub & 64) ? 65 : 0;
        reinterpret_cast<uint*>(&pro[rr][q][0])[sub & 63] = 0u;
    }
#pragma unroll
    for (int it = 0; it < 6; ++it) {
        int i   = t + it * 512;
        int rr  = i >> 10;
        int rem = i & 1023;
        int pos = rem >> 4;
        int ch  = rem & 15;
        int yr  = ho - 1 + rr;
        short8 val = {};
        if (yr >= 0 && yr < H_)
            val = *reinterpret_cast<const short8*>(
                xtb + (((size_t)((yr << 6) + pos)) << 7) + ch * 8);
        int q = pos + 1;
        *reinterpret_cast<short8*>(
            &pro[rr][q][(ch * 8) ^ ((q & 7) << 3)]) = val;
    }
    __syncthreads();

    // ================= offset-conv MFMA (B from LDS, no masking) ===========
    {
        const int wmO = wid >> 2, wnO = wid & 3;  // M=32 (2x16), N=64 (4x16)
        const int colq = wnO * 16 + arow;         // output position s
        f32x4 o0 = {}, o1 = {};
#pragma unroll
        for (int k = 0; k < K2_; ++k) {
            const int ky = k / 3, kx = k % 3;
            const int qr  = colq + kx;            // LDS row = s + kx (0..65)
            const int key = (qr & 7) << 3;
            const ushort* ap = wt_off
                + (((size_t)(k * 32 + wmO * 16 + arow)) << 7) + akk;
#pragma unroll
            for (int kc = 0; kc < 4; ++kc) {
                short8 aO = *reinterpret_cast<const short8*>(ap + kc * 32);
                short8 bO = *reinterpret_cast<const short8*>(
                    &pro[ky][qr][(kc * 32 + akk) ^ key]);
                if (kc < 2) o0 = __builtin_amdgcn_mfma_f32_16x16x32_bf16(aO, bO, o0, 0, 0, 0);
                else        o1 = __builtin_amdgcn_mfma_f32_16x16x32_bf16(aO, bO, o1, 0, 0, 0);
            }
        }
        const int sO = wnO * 16 + arow;
#pragma unroll
        for (int r4 = 0; r4 < 4; ++r4) {
            int j = wmO * 16 + ((lane >> 4) << 2) + r4;
            if (j < JOFF_) s_off[j][sO] = o0[r4] + o1[r4] + b_off[j];
        }
    }
    __syncthreads();   // publishes s_off; retires pro (sB may now be written)

    // ================= fused gather + MFMA main loop =================
    f32x4  acc[4] = {};
    short8 aC[4], aN[4];
    short8 gA[4][2], gB[4][2];               // two static buffer sets
    float  cA[4], cB[4];                     // bilinear coefs per set

    auto load_a = [&](int k, short8* dst) {
        const ushort* wk = wt + (size_t)k * (COUT_ * C_)
                         + (wid * 16 + arow) * C_ + akk;
#pragma unroll
        for (int kc = 0; kc < 4; ++kc)
            dst[kc] = *reinterpret_cast<const short8*>(wk + kc * 32);
    };

    // issue 8 lane-adjacent 16B corner loads (16 ch: chunks gq, gq+8)
    auto gather_load = [&](int k, short8 (&g)[4][2], float (&ca)[4]) {
        float dy = s_off[2*k    ][gp];
        float dx = s_off[2*k + 1][gp];
        float py = (float)(ho - 1 + k/3) + dy;
        float px = (float)(gp - 1 + k%3) + dx;
        float y0f = floorf(py), x0f = floorf(px);
        float wy = py - y0f,    wx = px - x0f;
        int y0 = (int)y0f, x0 = (int)x0f;
        int y1 = y0 + 1,   x1 = x0 + 1;
        float vy0 = (y0 >= 0 && y0 < H_) ? 1.f : 0.f;
        float vy1 = (y1 >= 0 && y1 < H_) ? 1.f : 0.f;
        float vx0 = (x0 >= 0 && x0 < W_) ? 1.f : 0.f;
        float vx1 = (x1 >= 0 && x1 < W_) ? 1.f : 0.f;
        int y0c = min(max(y0, 0), H_-1), y1c = min(max(y1, 0), H_-1);
        int x0c = min(max(x0, 0), W_-1), x1c = min(max(x1, 0), W_-1);
        int bx  = min(max(x0, 0), W_-2);     // column pair [bx, bx+1]
        float wx0 = (1.f - wx) * vx0, wx1 = wx * vx1;
        float ex0 = (x0c == bx ? wx0 : 0.f) + (x1c == bx ? wx1 : 0.f);
        float ex1 = (x0c == bx ? 0.f : wx0) + (x1c == bx ? 0.f : wx1);
        float r0 = (1.f - wy) * vy0, r1 = wy * vy1;
        ca[0] = r0*ex0; ca[1] = r0*ex1; ca[2] = r1*ex0; ca[3] = r1*ex1;
        const ushort* r00 = xtb + (((y0c << 6) + bx) << 7) + gq * 8;
        const ushort* r10 = xtb + (((y1c << 6) + bx) << 7) + gq * 8;
        g[0][0] = *reinterpret_cast<const short8*>(r00);        // (y0,bx)  lo
        g[0][1] = *reinterpret_cast<const short8*>(r00 + 64);   // (y0,bx)  hi
        g[1][0] = *reinterpret_cast<const short8*>(r00 + 128);  // (y0,bx+1)lo
        g[1][1] = *reinterpret_cast<const short8*>(r00 + 192);  // (y0,bx+1)hi
        g[2][0] = *reinterpret_cast<const short8*>(r10);        // (y1,bx)  lo
        g[2][1] = *reinterpret_cast<const short8*>(r10 + 64);   // (y1,bx)  hi
        g[3][0] = *reinterpret_cast<const short8*>(r10 + 128);  // (y1,bx+1)lo
        g[3][1] = *reinterpret_cast<const short8*>(r10 + 192);  // (y1,bx+1)hi
    };

    // combine corners, pack, two b128 stores (chunks gq, gq+8)
    auto gather_math_store = [&](int buf, const short8 (&g)[4][2],
                                 const float (&ca)[4]) {
#pragma unroll
        for (int j = 0; j < 2; ++j) {
            float v[8];
#pragma unroll
            for (int q = 0; q < 8; ++q) {
                float vv = ca[0] * bf2f((ushort)g[0][j][q]);
                vv = fmaf(ca[1], bf2f((ushort)g[1][j][q]), vv);
                vv = fmaf(ca[2], bf2f((ushort)g[2][j][q]), vv);
                vv = fmaf(ca[3], bf2f((ushort)g[3][j][q]), vv);
                v[q] = vv;
            }
            uint4 pk;
            pk.x = (uint)f2bf(v[0]) | ((uint)f2bf(v[1]) << 16);
            pk.y = (uint)f2bf(v[2]) | ((uint)f2bf(v[3]) << 16);
            pk.z = (uint)f2bf(v[4]) | ((uint)f2bf(v[5]) << 16);
            pk.w = (uint)f2bf(v[6]) | ((uint)f2bf(v[7]) << 16);
            *reinterpret_cast<uint4*>(
                &sB[buf][gp][(gq * 8 + j * 64) ^ swzp]) = pk;
        }
    };

    // ---- pipeline prologue: A(0); g(0)->gA; g(1)->gB; sB[0] from gA
    load_a(0, aC);
    gather_load(0, gA, cA);
    gather_load(1, gB, cB);
    gather_math_store(0, gA, cA);
    asm volatile("s_waitcnt lgkmcnt(0)" ::: "memory");
    __builtin_amdgcn_s_barrier();

#pragma unroll
    for (int k = 0; k < K2_; ++k) {
        if (k < K2_ - 1) load_a(k + 1, aN);
        if (k + 2 < K2_) {                       // g(k+2) -> buf[k&1] (dead)
            if ((k & 1) == 0) gather_load(k + 2, gA, cA);
            else              gather_load(k + 2, gB, cB);
        }

        // ---- MFMA(k): LDS B, register A (aC drained long ago)
        const int buf = k & 1;
#pragma unroll
        for (int kc = 0; kc < 4; ++kc) {
#pragma unroll
            for (int ni = 0; ni < 4; ++ni) {
                int srow = ni*16 + arow;
                short8 bF = *reinterpret_cast<const short8*>(
                    &sB[buf][srow][(kc*32 + akk) ^ ((srow & 15) << 3)]);
                acc[ni] = __builtin_amdgcn_mfma_f32_16x16x32_bf16(
                    aC[kc], bF, acc[ni], 0, 0, 0);
            }
        }

        if (k < K2_ - 1) {                       // math(k+1) from buf[(k+1)&1]
            if ((k & 1) == 0) gather_math_store((k + 1) & 1, gB, cB);
            else              gather_math_store((k + 1) & 1, gA, cA);
        }

        // RAW barrier: drain LDS ops only; VMEM prefetches stay in flight
        asm volatile("s_waitcnt lgkmcnt(0)" ::: "memory");
        __builtin_amdgcn_s_barrier();

        if (k < K2_ - 1) {
#pragma unroll
            for (int kc = 0; kc < 4; ++kc) aC[kc] = aN[kc];
        }
    }

    // ---- epilogue: C/D layout col=lane&15, row=(lane>>4)*4+reg; nt stores
#pragma unroll
    for (int ni = 0; ni < 4; ++ni) {
#pragma unroll
        for (int r = 0; r < 4; ++r) {
            int o = wid*16 + ((lane >> 4) << 2) + r;
            int s = ni*16 + arow;
            __builtin_nontemporal_store(acc[ni][r],
                &out[(((size_t)(b*COUT_ + o)) << 12) + hw0 + s]);
        }
    }
}

// ---------------------------------------------------------------------------
extern "C" void kernel_launch(void* const* d_in, const int* in_sizes, int n_in,
                              void* d_out, int out_size, void* d_ws, size_t ws_size,
                              hipStream_t stream) {
    const float* x     = (const float*)d_in[0];
    const float* w_off = (const float*)d_in[1];
    const float* b_off = (const float*)d_in[2];
    const float* w_def = (const float*)d_in[3];
    float* out  = (float*)d_out;

    char* ws = (char*)d_ws;
    ushort* xtp    = (ushort*)ws;                         // 8,388,608 B
    ushort* wt     = (ushort*)(ws + 8388608);             //   294,912 B
    ushort* wt_off = (ushort*)(ws + 8388608 + 294912);    //    73,728 B

    // Kernel X: x -> NHWC bf16
    nhwc_kernel<<<1024, 512, 0, stream>>>(x, xtp);
    // Kernel T: both weight transposes
    {
        int total  = K2_ * COUT_ * C_ + K2_ * 32 * C_;    // 184,320
        transpose_w_kernel<<<(total + 255) / 256, 256, 0, stream>>>(
            w_def, w_off, wt, wt_off);
    }
    // Kernel B: fused offsets + gather + MFMA GEMM (512 blocks, 64 pos each)
    deform_mfma_kernel<<<(B_ * HW_) / 64, 512, 0, stream>>>(
        xtp, wt, wt_off, b_off, out);
}